// Round 1
// baseline (39.478 us; speedup 1.0000x reference)
//
#include <hip/hip_runtime.h>
#include <hip/hip_bf16.h>

// Problem constants (B=131072 rows, C=64 cols)
#define NROWS 131072
#define NCOLS 64
#define NBLK_A 256          // blocks in kernel A (1 per CU)
#define THREADS_A 1024      // 16 waves per block
#define ROWS_PER_WAVE 32    // u32 mask batch; 256*16*32 = 131072 exactly
#define NGROUPS 8           // reduction groups in B1
#define PK_CELLS 4096       // packed u16-pair cells per block (2048 S + 2048 P)

// -------- Kernel A: fused focal loss + Gram (S = t^T t, P = v^T w) --------
// Packing: per wave, counts for i in [0,64) are byte-packed (4 per u32, cnt<=32).
// LDS: u16-pair-packed per (i-pair, j) cell; 16 waves reduced via LDS atomics.
// Flush: per-block partial (packed u16 pairs) OR global u32 atomics (fallback).
template<bool ATOMIC_FLUSH>
__global__ __launch_bounds__(THREADS_A, 4)
void kernA(const float* __restrict__ in, const float* __restrict__ tg,
           const float* __restrict__ pw, double* __restrict__ focal_acc,
           unsigned* __restrict__ pk,           // partial path: pk[block][4096]
           unsigned* __restrict__ gS,           // atomic path: S cells u32[4096]
           unsigned* __restrict__ gP) {         // atomic path: P cells u32[4096]
    __shared__ unsigned ldsSP[PK_CELLS];  // [0..2047]=S packed, [2048..4095]=P packed
    __shared__ float fpart[16];
    const int tid = threadIdx.x;
    for (int k = tid; k < PK_CELLS; k += THREADS_A) ldsSP[k] = 0u;
    __syncthreads();

    const int lane = tid & 63;
    const int wv = tid >> 6;                      // 0..15
    const int row0 = blockIdx.x * (16 * ROWS_PER_WAVE) + wv * ROWS_PER_WAVE;
    const float pwl = pw[lane];
    const float* inp = in + (size_t)row0 * NCOLS + lane;
    const float* tgp = tg + (size_t)row0 * NCOLS + lane;

    float fsum = 0.f;
    unsigned m = 0u, v = 0u;
#pragma unroll 8
    for (int r = 0; r < ROWS_PER_WAVE; ++r) {
        float x = inp[r * NCOLS];
        float t = tgp[r * NCOLS];
        float ax = fabsf(x);
        float e = __expf(-ax);                // exp(-|x|)
        float L = __logf(1.f + e);            // log1p(exp(-|x|)), no cancellation
        float inv = 1.f / (1.f + e);          // sigmoid(|x|)  (the "large" prob)
        float q = e * inv;                    // 1 - sigmoid(|x|) (the "small" prob)
        bool tb = t > 0.5f;
        bool pb = x >= 0.f;
        float w = (tb == pb) ? q : inv;       // 1 - p_t
        float bce = tb ? pwl * (L + fmaxf(-x, 0.f)) : (L + fmaxf(x, 0.f));
        fsum += w * w * bce;
        unsigned bt = tb ? 1u : 0u;
        unsigned bv = (tb && pb) ? 1u : 0u;
        m |= bt << r;
        v |= bv << r;
    }
    const unsigned wm = m & ~v;               // t=1, pred=0

    unsigned accS[16], accP[16];
#pragma unroll
    for (int k = 0; k < 16; ++k) { accS[k] = 0u; accP[k] = 0u; }
#pragma unroll
    for (int i = 0; i < 64; ++i) {
        unsigned mi = (unsigned)__builtin_amdgcn_readlane((int)m, i);
        unsigned vi = (unsigned)__builtin_amdgcn_readlane((int)v, i);
        accS[i >> 2] += (unsigned)__popc(mi & m)  << (8 * (i & 3));  // S[i][lane]
        accP[i >> 2] += (unsigned)__popc(vi & wm) << (8 * (i & 3));  // P[i][lane]
    }

    // LDS reduce across the 16 waves (u16-pair packed; max 16*32=512 < 65536)
#pragma unroll
    for (int k = 0; k < 16; ++k) {
        unsigned aS = accS[k], aP = accP[k];
        atomicAdd(&ldsSP[(2 * k + 0) * 64 + lane],
                  (aS & 0xFFu) | (((aS >> 8) & 0xFFu) << 16));
        atomicAdd(&ldsSP[(2 * k + 1) * 64 + lane],
                  ((aS >> 16) & 0xFFu) | (((aS >> 24) & 0xFFu) << 16));
        atomicAdd(&ldsSP[2048 + (2 * k + 0) * 64 + lane],
                  (aP & 0xFFu) | (((aP >> 8) & 0xFFu) << 16));
        atomicAdd(&ldsSP[2048 + (2 * k + 1) * 64 + lane],
                  ((aP >> 16) & 0xFFu) | (((aP >> 24) & 0xFFu) << 16));
    }

    // focal: wave reduce then block reduce
#pragma unroll
    for (int off = 32; off; off >>= 1) fsum += __shfl_down(fsum, off, 64);
    if (lane == 0) fpart[wv] = fsum;
    __syncthreads();

    if (tid == 0) {
        float tot = 0.f;
#pragma unroll
        for (int k = 0; k < 16; ++k) tot += fpart[k];
        atomicAdd(focal_acc, (double)tot);
    }

    if (!ATOMIC_FLUSH) {
        unsigned* dst = pk + (size_t)blockIdx.x * PK_CELLS;
        for (int k = tid; k < PK_CELLS; k += THREADS_A) dst[k] = ldsSP[k];
    } else {
        for (int k = tid; k < 2048; k += THREADS_A) {
            int ip = k >> 6, j = k & 63;
            unsigned s = ldsSP[k], p = ldsSP[2048 + k];
            atomicAdd(&gS[(2 * ip + 0) * 64 + j], s & 0xFFFFu);
            atomicAdd(&gS[(2 * ip + 1) * 64 + j], s >> 16);
            atomicAdd(&gP[(2 * ip + 0) * 64 + j], p & 0xFFFFu);
            atomicAdd(&gP[(2 * ip + 1) * 64 + j], p >> 16);
        }
    }
}

// -------- B1: reduce 256 block-partials into 8 unpacked group sums --------
__global__ void kernB1(const unsigned* __restrict__ pk, unsigned* __restrict__ red) {
    int t = blockIdx.x * 256 + threadIdx.x;   // 0..32767 = 8 groups x 4096 cells
    int g = t >> 12;
    int pc = t & 4095;
    unsigned lo = 0u, hi = 0u;
    const unsigned* p = pk + (size_t)(g * 32) * PK_CELLS + pc;
#pragma unroll 8
    for (int b = 0; b < 32; ++b) {
        unsigned val = p[(size_t)b * PK_CELLS];
        lo += val & 0xFFFFu;
        hi += val >> 16;
    }
    int mat = pc >> 11;                // 0=S, 1=P
    int e = pc & 2047;
    int ip = e >> 6, j = e & 63;
    unsigned* out = red + (size_t)g * 8192 + mat * 4096;
    out[(2 * ip + 0) * 64 + j] = lo;
    out[(2 * ip + 1) * 64 + j] = hi;
}

// -------- B2: finish S,P; compute penalty = sum corr_ij * P_ij (thresholded) ----
__global__ void kernB2(const unsigned* __restrict__ red, double* __restrict__ pen_acc) {
    int c = blockIdx.x * 256 + threadIdx.x;   // 0..4095 cell (i,j)
    unsigned S = 0u, P = 0u;
#pragma unroll
    for (int g = 0; g < NGROUPS; ++g) {
        S += red[g * 8192 + c];
        P += red[g * 8192 + 4096 + c];
    }
    int i = c >> 6, j = c & 63;
    float corr = (float)S * (1.0f / (float)NROWS);
    // penalty_total = 2 * sum A_ij P_ij, A = 0.5*corr (thresholded) => corr*P
    double contrib = (i != j && corr > 0.3f) ? (double)corr * (double)P : 0.0;
#pragma unroll
    for (int off = 32; off; off >>= 1) contrib += __shfl_down(contrib, off, 64);
    __shared__ double dpart[4];
    int lane = threadIdx.x & 63, wv = threadIdx.x >> 6;
    if (lane == 0) dpart[wv] = contrib;
    __syncthreads();
    if (threadIdx.x == 0)
        atomicAdd(pen_acc, dpart[0] + dpart[1] + dpart[2] + dpart[3]);
}

// B2 variant for the atomic-fallback path (reads final S,P directly)
__global__ void kernB2d(const unsigned* __restrict__ gS, const unsigned* __restrict__ gP,
                        double* __restrict__ pen_acc) {
    int c = blockIdx.x * 256 + threadIdx.x;
    unsigned S = gS[c], P = gP[c];
    int i = c >> 6, j = c & 63;
    float corr = (float)S * (1.0f / (float)NROWS);
    double contrib = (i != j && corr > 0.3f) ? (double)corr * (double)P : 0.0;
#pragma unroll
    for (int off = 32; off; off >>= 1) contrib += __shfl_down(contrib, off, 64);
    __shared__ double dpart[4];
    int lane = threadIdx.x & 63, wv = threadIdx.x >> 6;
    if (lane == 0) dpart[wv] = contrib;
    __syncthreads();
    if (threadIdx.x == 0)
        atomicAdd(pen_acc, dpart[0] + dpart[1] + dpart[2] + dpart[3]);
}

// -------- C: finalize --------
__global__ void kernC(const double* __restrict__ focal, const double* __restrict__ pen,
                      float* __restrict__ out) {
    out[0] = (float)((focal[0] + pen[0]) * (1.0 / (double)((size_t)NROWS * NCOLS)));
}

extern "C" void kernel_launch(void* const* d_in, const int* in_sizes, int n_in,
                              void* d_out, int out_size, void* d_ws, size_t ws_size,
                              hipStream_t stream) {
    const float* in = (const float*)d_in[0];
    const float* tg = (const float*)d_in[1];
    const float* pw = (const float*)d_in[2];
    float* out = (float*)d_out;
    char* ws = (char*)d_ws;
    double* focal = (double*)ws;
    double* pen = (double*)(ws + 8);

    const size_t pk_bytes = (size_t)NBLK_A * PK_CELLS * sizeof(unsigned);     // 4 MB
    const size_t red_bytes = (size_t)NGROUPS * 8192 * sizeof(unsigned);       // 256 KB
    const size_t need = 64 + pk_bytes + red_bytes;

    hipMemsetAsync(ws, 0, 64, stream);  // zero focal_acc, pen_acc

    if (ws_size >= need) {
        unsigned* pk = (unsigned*)(ws + 64);
        unsigned* red = (unsigned*)(ws + 64 + pk_bytes);
        kernA<false><<<NBLK_A, THREADS_A, 0, stream>>>(in, tg, pw, focal, pk, nullptr, nullptr);
        kernB1<<<(NGROUPS * 4096) / 256, 256, 0, stream>>>(pk, red);
        kernB2<<<16, 256, 0, stream>>>(red, pen);
    } else {
        // fallback: needs only 64 + 32 KB of workspace
        unsigned* gS = (unsigned*)(ws + 64);
        unsigned* gP = gS + 4096;
        hipMemsetAsync(ws + 64, 0, 8192 * sizeof(unsigned), stream);
        kernA<true><<<NBLK_A, THREADS_A, 0, stream>>>(in, tg, pw, focal, nullptr, gS, gP);
        kernB2d<<<16, 256, 0, stream>>>(gS, gP, pen);
    }
    kernC<<<1, 1, 0, stream>>>(focal, pen, out);
}